// Round 11
// baseline (81.749 us; speedup 1.0000x reference)
//
#include <hip/hip_runtime.h>
#include <math.h>

#define N_STEPS 10240
#define ROWF2 264          // float2 slots per IMP row (257 used, padded)
#define ROWF  (ROWF2*2)    // floats per IMP row = 528 (2112 B)
#define SROWF 512          // floats per S row (bins 0..255; Nyquist in S256a)
#define ENV_N 327744       // N_FRAMES*32
#define LCH 16             // scan chunk length
#define KWARM 16           // warm-up steps (contraction 0.283^16 ~ 1.6e-9 rel)

typedef float f4  __attribute__((ext_vector_type(4)));
typedef float f4a __attribute__((ext_vector_type(4), aligned(4)));

__device__ inline float2 mkf2(float x, float y) { return make_float2(x, y); }

// ---------------- wave-level complex FFT-256: 64 lanes, 4 float2 regs -------
template<int DIR>
__device__ inline void waveFFT256(float2 v[4], const int l,
                                  const float Tc, const float Ts,
                                  const float ux, const float uy) {
  const int rb = (int)(__brev((unsigned)l) >> 26);
  #pragma unroll
  for (int r = 0; r < 4; ++r) {
    v[r].x = __shfl(v[r].x, rb);
    v[r].y = __shfl(v[r].y, rb);
  }
  #pragma unroll
  for (int s = 0; s < 6; ++s) {
    const int half = 1 << s;
    float wx, wy;
    if (s == 0) { wx = (l & 1) ? -1.f : 1.f; wy = 0.f; }
    else {
      const int idx = (l << (5 - s)) & 63;
      wx = __shfl(Tc, idx);
      float tsv = __shfl(Ts, idx);
      wy = (DIR < 0) ? tsv : -tsv;
    }
    #pragma unroll
    for (int r = 0; r < 4; ++r) {
      float tx = __shfl_xor(v[r].x, half);
      float ty = __shfl_xor(v[r].y, half);
      const bool low = (l & half) == 0;
      float ax = low ? v[r].x : tx, ay = low ? v[r].y : ty;
      float bx = low ? tx : v[r].x, by = low ? ty : v[r].y;
      v[r].x = ax + (wx * bx - wy * by);
      v[r].y = ay + (wx * by + wy * bx);
    }
  }
  const float u2x = ux * ux - uy * uy, u2y = 2.f * ux * uy;
  const float u3x = u2x * ux - u2y * uy, u3y = u2x * uy + u2y * ux;
  float2 t0 = v[0];
  float2 t1 = mkf2(v[1].x * ux - v[1].y * uy, v[1].x * uy + v[1].y * ux);
  float2 t2 = mkf2(v[2].x * u2x - v[2].y * u2y, v[2].x * u2y + v[2].y * u2x);
  float2 t3 = mkf2(v[3].x * u3x - v[3].y * u3y, v[3].x * u3y + v[3].y * u3x);
  float2 p02 = mkf2(t0.x + t2.x, t0.y + t2.y), m02 = mkf2(t0.x - t2.x, t0.y - t2.y);
  float2 p13 = mkf2(t1.x + t3.x, t1.y + t3.y), m13 = mkf2(t1.x - t3.x, t1.y - t3.y);
  v[0] = mkf2(p02.x + p13.x, p02.y + p13.y);
  v[2] = mkf2(p02.x - p13.x, p02.y - p13.y);
  if (DIR < 0) {
    v[1] = mkf2(m02.x + m13.y, m02.y - m13.x);
    v[3] = mkf2(m02.x - m13.y, m02.y + m13.x);
  } else {
    v[1] = mkf2(m02.x - m13.y, m02.y + m13.x);
    v[3] = mkf2(m02.x + m13.y, m02.y - m13.x);
  }
}

// ---------------- kernel A: impulse spectra (one wave per step j) -----------
__global__ __launch_bounds__(256) void kernA(const float* __restrict__ env,
                                             const float* __restrict__ noise,
                                             const float* __restrict__ tf_re,
                                             const float* __restrict__ etf_re,
                                             const float* __restrict__ etf_im,
                                             float* __restrict__ IMP,
                                             float* __restrict__ T256,
                                             float* __restrict__ I256) {
  const int l = threadIdx.x & 63;
  const int j = blockIdx.x * 4 + (threadIdx.x >> 6);
  float* rowf = IMP + (size_t)j * ROWF;
  float2* row = (float2*)rowf;
  if (j >= N_STEPS) {
    if (j == N_STEPS) {                  // row N_STEPS = 0 (tail phase reads it)
      #pragma unroll
      for (int r = 0; r < 4; ++r) row[64 * r + l] = mkf2(0.f, 0.f);
      if (l == 0) { row[256] = mkf2(0.f, 0.f); I256[N_STEPS] = 0.f; }
    }
    return;
  }
  const int K = 32 * j + l;
  float e0 = env[K];                e0 *= e0;
  float em = env[max(K - 1, 0)];    em *= em;
  float ep = env[min(K + 1, ENV_N - 1)]; ep *= ep;
  float sm[8];
  #pragma unroll
  for (int u = 0; u < 8; ++u) {
    float val;
    if (u < 4) {
      float fr = 0.5625f + 0.125f * (float)u;
      val = em * (1.f - fr) + e0 * fr;
      if (K == 0) val = e0;              // ref clamps coords at 0
    } else {
      float fr = 0.0625f + 0.125f * (float)(u - 4);
      val = e0 * (1.f - fr) + ep * fr;
    }
    sm[u] = val;
  }
  const float4* np = (const float4*)(noise + (size_t)j * 512 + 8 * l);
  float4 n0 = np[0], n1 = np[1];
  float nn[8] = {n0.x, n0.y, n0.z, n0.w, n1.x, n1.y, n1.z, n1.w};
  float2 v[4];
  #pragma unroll
  for (int r = 0; r < 4; ++r)
    v[r] = mkf2(nn[2 * r] * sm[2 * r], nn[2 * r + 1] * sm[2 * r + 1]);

  float ca, sa; sincosf(-0.01227184630308513f * (float)l, &sa, &ca);
  const float ux = ca * ca - sa * sa, uy = 2.f * ca * sa;
  float Tc, Ts; sincosf(-0.09817477042468103f * (float)l, &Ts, &Tc);

  waveFFT256<-1>(v, l, Tc, Ts, ux, uy);  // v[r] = Z[64r + l]

  float2 Zc[4];
  const int pidx = (64 - l) & 63;
  #pragma unroll
  for (int r = 0; r < 4; ++r) {
    Zc[r].x = __shfl(v[3 - r].x, pidx);
    Zc[r].y = __shfl(v[3 - r].y, pidx);
  }
  float2 z0lane = v[0];
  if (l == 0) { Zc[0] = v[0]; Zc[1] = v[3]; Zc[2] = v[2]; Zc[3] = v[1]; }
  constexpr float crA[4] = {1.f, 0.7071067811865476f, 0.f, -0.7071067811865476f};
  constexpr float srA[4] = {0.f, -0.7071067811865476f, -1.f, -0.7071067811865476f};
  const float FS = 0.04419417382415922f;                  // 1/sqrt(512)
  #pragma unroll
  for (int r = 0; r < 4; ++r) {
    float Ex = 0.5f * (v[r].x + Zc[r].x), Ey = 0.5f * (v[r].y - Zc[r].y);
    float Dx = v[r].x - Zc[r].x,          Dy = v[r].y + Zc[r].y;
    float Ox = 0.5f * Dy, Oy = -0.5f * Dx;
    float c  = crA[r] * ca - srA[r] * sa;                 // e^{-i pi k/256}
    float sn = crA[r] * sa + srA[r] * ca;
    float Wx = (Ex + (c * Ox - sn * Oy)) * FS;
    float Wy = (Ey + (c * Oy + sn * Ox)) * FS;
    int k = 64 * r + l;
    float er = etf_re[k], ei = etf_im[k];
    float Px = Wx * er - Wy * ei;
    float Py = Wx * ei + Wy * er;
    if (k == 0) Py = 0.f;                // irfft drops Im at DC
    row[k] = mkf2(Px, Py);
  }
  if (l == 0) {
    float W256 = (z0lane.x - z0lane.y) * FS;
    float imp256 = W256 * etf_re[256];
    row[256] = mkf2(imp256, 0.f);
    I256[j] = imp256;
    T256[j] = tf_re[(size_t)j * 257 + 256];
  }
}

// ---------------- kernel B: scan with phase-bursted LDS staging -------------
// Two phases of 16 steps. Each phase: burst-copy 64 KB (tf/IMP rows) to LDS,
// then 16 steps pure LDS+shuffle (no global ops in the serial chain at all).
// State rows are written into the dead IMP LDS slots, stored once at the end.
__device__ inline void doStep(const f4& tr, const f4& ti,
                              const float4& ia, const float4& ib,
                              int l, float tfr256, float imp256,
                              float2& s0, float2& s1, float2& s2, float2& s3,
                              float& s256) {
  float2 y0, y1, y2, y3;
  y0.x = s0.x * tr[0] - s0.y * ti[0];  y0.y = s0.x * ti[0] + s0.y * tr[0];
  y1.x = s1.x * tr[1] - s1.y * ti[1];  y1.y = s1.x * ti[1] + s1.y * tr[1];
  y2.x = s2.x * tr[2] - s2.y * ti[2];  y2.y = s2.x * ti[2] + s2.y * tr[2];
  y3.x = s3.x * tr[3] - s3.y * ti[3];  y3.y = s3.x * ti[3] + s3.y * tr[3];
  if (l == 0) y0.y = 0.f;              // drop Im at DC (irfft semantics)
  float Y256 = tfr256 * s256;          // Nyquist, real (wave-uniform)
  float phx = __shfl_up(y3.x, 1), phy = __shfl_up(y3.y, 1);
  float nlx = __shfl_down(y0.x, 1), nly = __shfl_down(y0.y, 1);
  float2 p0 = (l == 0)  ? mkf2(y1.x, -y1.y) : mkf2(phx, phy);  // Y_{-1} = conj(Y_1)
  float2 n3 = (l == 63) ? mkf2(Y256, 0.f)   : mkf2(nlx, nly);  // Y_256 (real)
  float y255x = __shfl(y3.x, 63);
  const float A = 0.54f, Bc = 0.23f;
  float2 c0, c1, c2, c3;
  c0.x = A * y0.x - Bc * (p0.x + y1.x);  c0.y = A * y0.y - Bc * (p0.y + y1.y);
  c1.x = A * y1.x - Bc * (y0.x + y2.x);  c1.y = A * y1.y - Bc * (y0.y + y2.y);
  c2.x = A * y2.x - Bc * (y1.x + y3.x);  c2.y = A * y2.y - Bc * (y1.y + y3.y);
  c3.x = A * y3.x - Bc * (y2.x + n3.x);  c3.y = A * y3.y - Bc * (y2.y + n3.y);
  float C256 = A * Y256 - 0.46f * y255x;
  s0.x = c0.x + ia.x;  s0.y = c0.y + ia.y;
  s1.x = c1.x + ia.z;  s1.y = c1.y + ia.w;
  s2.x = c2.x + ib.x;  s2.y = c2.y + ib.y;
  s3.x = c3.x + ib.z;  s3.y = c3.y + ib.w;
  s256 = C256 + imp256;
}

__global__ __launch_bounds__(64) void kernB(const float* __restrict__ tf_re,
                                            const float* __restrict__ tf_im,
                                            const float* __restrict__ IMP,
                                            const float* __restrict__ T256,
                                            const float* __restrict__ I256,
                                            float* __restrict__ S,
                                            float* __restrict__ S256a) {
  const int c = blockIdx.x, l = threadIdx.x;
  const int j0 = c * LCH;
  const int w0 = (c > 0) ? (j0 - KWARM) : j0;
  const int WOFF = (c > 0) ? KWARM : 0;

  __shared__ float4 TFRE[16][64];    // 16 KB: tf_re rows (bins 0..255)
  __shared__ float4 TFIM[16][64];    // 16 KB
  __shared__ float4 IMRW[16][128];   // 32 KB: IMP rows; reused as S-row output

  float t256v = T256[min(w0 + l, N_STEPS - 1)];   // lane m <-> step w0+m
  float i256v = I256[min(w0 + 1 + l, N_STEPS)];

  float2 s0 = mkf2(0.f, 0.f), s1 = s0, s2 = s0, s3 = s0;
  float s256 = 0.f, s256keep = 0.f;

  if (c == 0) {                          // exact init: S_0 = IMP_0; store S row 0
    const float4* r4 = (const float4*)IMP;
    float4 a = r4[2 * l], bb = r4[2 * l + 1];
    s0 = mkf2(a.x, a.y);  s1 = mkf2(a.z, a.w);
    s2 = mkf2(bb.x, bb.y); s3 = mkf2(bb.z, bb.w);
    s256 = IMP[512];
    float4* o4 = (float4*)S;
    o4[2 * l] = a; o4[2 * l + 1] = bb;
    if (l == 0) S256a[0] = s256;
  }

  // ---- burst: copy rows [base, base+16) into LDS (global traffic only here)
  #define BURST(base) { \
    _Pragma("unroll") \
    for (int k = 0; k < 16; ++k) { \
      const int i = (base) + k; \
      f4a vr = *(const f4a*)(tf_re + (size_t)i * 257 + 4 * l); \
      f4a vi = *(const f4a*)(tf_im + (size_t)i * 257 + 4 * l); \
      TFRE[k][l] = make_float4(vr[0], vr[1], vr[2], vr[3]); \
      TFIM[k][l] = make_float4(vi[0], vi[1], vi[2], vi[3]); \
      const float4* ims = (const float4*)(IMP + (size_t)(i + 1) * ROWF); \
      IMRW[k][2 * l]     = ims[2 * l]; \
      IMRW[k][2 * l + 1] = ims[2 * l + 1]; \
    } }

  // ---- consume 16 steps from LDS; SAVE: overwrite dead IMP slot with state
  #define CONSUME(boff, SAVE) { \
    for (int k = 0; k < 16; ++k) { \
      float4 trf = TFRE[k][l], tif = TFIM[k][l]; \
      f4 tr, ti; \
      tr[0] = trf.x; tr[1] = trf.y; tr[2] = trf.z; tr[3] = trf.w; \
      ti[0] = tif.x; ti[1] = tif.y; ti[2] = tif.z; ti[3] = tif.w; \
      float4 ia = IMRW[k][2 * l], ib = IMRW[k][2 * l + 1]; \
      const float tfr_ = __shfl(t256v, (boff) + k); \
      const float im2_ = __shfl(i256v, (boff) + k); \
      doStep(tr, ti, ia, ib, l, tfr_, im2_, s0, s1, s2, s3, s256); \
      if (SAVE) { \
        IMRW[k][2 * l]     = make_float4(s0.x, s0.y, s1.x, s1.y); \
        IMRW[k][2 * l + 1] = make_float4(s2.x, s2.y, s3.x, s3.y); \
        if (l == k) s256keep = s256; \
      } \
    } }

  if (c > 0) {           // warm-up phase (steps w0..w0+15), no output
    BURST(w0)
    CONSUME(0, false)
  }
  BURST(j0)              // main phase (steps j0..j0+15)
  CONSUME(WOFF, true)

  #undef BURST
  #undef CONSUME

  // ---- store phase: LDS state rows -> S (single pass) ----
  for (int k = 0; k < 16; ++k) {
    float4* o4 = (float4*)(S + (size_t)(j0 + 1 + k) * SROWF + 8 * l);
    o4[0] = IMRW[k][2 * l];
    o4[1] = IMRW[k][2 * l + 1];
  }
  if (l < LCH) S256a[j0 + 1 + l] = s256keep;
}

// ---------------- kernel C: irfft + overlap-add, fused (parallel) ----------
__global__ __launch_bounds__(576) void kernC(const float* __restrict__ S,
                                             const float* __restrict__ S256a,
                                             float* __restrict__ out) {
  const int l = threadIdx.x & 63;
  const int w = threadIdx.x >> 6;                      // 0..8
  const int b = blockIdx.x;                            // 0..1279
  const int r = 8 * b - 1 + w;                         // -1 .. 10239
  __shared__ float2 ybuf[9][256];
  if (r < 0) {
    #pragma unroll
    for (int rr = 0; rr < 4; ++rr) ybuf[0][64 * rr + l] = mkf2(0.f, 0.f);
  } else {
    const float4* r4 = (const float4*)(S + (size_t)r * SROWF);
    float4 a = r4[2 * l], bb = r4[2 * l + 1];
    float2 W[4] = {mkf2(a.x, a.y), mkf2(a.z, a.w), mkf2(bb.x, bb.y), mkf2(bb.z, bb.w)};
    float w256 = S256a[r];
    float2 Wm[4];
    const int pidx = (64 - l) & 63;
    Wm[0].x = __shfl(W[0].x, pidx);
    Wm[0].y = __shfl(W[0].y, pidx);
    if (l == 0) Wm[0] = mkf2(w256, 0.f);
    Wm[1].x = __shfl_xor(W[3].x, 63);  Wm[1].y = __shfl_xor(W[3].y, 63);
    Wm[2].x = __shfl_xor(W[2].x, 63);  Wm[2].y = __shfl_xor(W[2].y, 63);
    Wm[3].x = __shfl_xor(W[1].x, 63);  Wm[3].y = __shfl_xor(W[1].y, 63);
    float cu, su; sincosf(0.02454369260617026f * (float)l, &su, &cu);
    const float cl = cu * cu - su * su, sl_ = 2.f * cu * su;
    float Tc, Ts; sincosf(-0.09817477042468103f * (float)l, &Ts, &Tc);
    constexpr float crC[4] = {1.f, 0.9999247018391445f, 0.9996988186962042f, 0.9993223845883495f};
    constexpr float srC[4] = {0.f, 0.0122715382857199f, 0.0245412285229123f, 0.0368072229413588f};
    float2 v[4];
    #pragma unroll
    for (int rr = 0; rr < 4; ++rr) {
      float Ex = 0.5f * (W[rr].x + Wm[rr].x), Ey = 0.5f * (W[rr].y - Wm[rr].y);
      float Dx = W[rr].x - Wm[rr].x,          Dy = W[rr].y + Wm[rr].y;
      float c  = cl * crC[rr] - sl_ * srC[rr];
      float sn = cl * srC[rr] + sl_ * crC[rr];
      float Ox = 0.5f * (c * Dx - sn * Dy);
      float Oy = 0.5f * (c * Dy + sn * Dx);
      v[rr] = mkf2(Ex - Oy, Ey + Ox);
    }
    waveFFT256<+1>(v, l, Tc, Ts, cu, su);
    const float ISC = 0.08838834764831845f;  // sqrt(512)/256
    #pragma unroll
    for (int rr = 0; rr < 4; ++rr)
      ybuf[w][64 * rr + l] = mkf2(v[rr].x * ISC, v[rr].y * ISC);
  }
  __syncthreads();
  float2* out2 = (float2*)out;
  const size_t base = (size_t)b * 1024;
  for (int idx = threadIdx.x; idx < 1024; idx += 576) {
    const int k = idx >> 7, t2 = idx & 127;
    float2 a = ybuf[k + 1][t2];
    float2 p = ybuf[k][128 + t2];
    out2[base + idx] = mkf2(a.x + p.x, a.y + p.y);
  }
}

// ---------------- launch ----------------
extern "C" void kernel_launch(void* const* d_in, const int* in_sizes, int n_in,
                              void* d_out, int out_size, void* d_ws, size_t ws_size,
                              hipStream_t stream) {
  const float* env    = (const float*)d_in[1];
  const float* tf_re  = (const float*)d_in[2];
  const float* tf_im  = (const float*)d_in[3];
  const float* etf_re = (const float*)d_in[4];
  const float* etf_im = (const float*)d_in[5];
  const float* noise  = (const float*)d_in[6];
  float* out = (float*)d_out;

  float* wsf = (float*)d_ws;
  float* IMP   = wsf;                                       // (N_STEPS+1) x ROWF
  float* S     = wsf + (size_t)(N_STEPS + 1) * ROWF;        // (N_STEPS+1) x SROWF
  float* T256  = S + (size_t)(N_STEPS + 1) * SROWF;         // N_STEPS
  float* I256  = T256 + N_STEPS;                            // N_STEPS+1
  float* S256a = I256 + (N_STEPS + 1);                      // N_STEPS+1
  // ws use: 10241*2112 + 10241*2048 + ~123 KB ~= 42.7 MB

  kernA<<<(N_STEPS / 4) + 1, 256, 0, stream>>>(env, noise, tf_re, etf_re, etf_im,
                                               IMP, T256, I256);
  kernB<<<N_STEPS / LCH, 64, 0, stream>>>(tf_re, tf_im, IMP, T256, I256, S, S256a);
  kernC<<<N_STEPS / 8, 576, 0, stream>>>(S, S256a, out);
}

// Round 12
// 61.200 us; speedup vs baseline: 1.3358x; 1.3358x over previous
//
#include <hip/hip_runtime.h>
#include <math.h>

#define N_STEPS 10240
#define ROWF2 264          // float2 slots per spectral row (257 used, padded)
#define ROWF  (ROWF2*2)    // floats per row = 528
#define ENV_N 327744       // N_FRAMES*32
#define LCH 8              // scan chunk length: 1280 chunks -> 5 waves/CU
#define KWARM 16           // warm-up steps (contraction 0.283^16 ~ 1.6e-9 rel)

typedef float f4a __attribute__((ext_vector_type(4), aligned(4)));

__device__ inline float2 mkf2(float x, float y) { return make_float2(x, y); }

// ---------------- wave-level complex FFT-256: 64 lanes, 4 float2 regs -------
template<int DIR>
__device__ inline void waveFFT256(float2 v[4], const int l,
                                  const float Tc, const float Ts,
                                  const float ux, const float uy) {
  const int rb = (int)(__brev((unsigned)l) >> 26);
  #pragma unroll
  for (int r = 0; r < 4; ++r) {
    v[r].x = __shfl(v[r].x, rb);
    v[r].y = __shfl(v[r].y, rb);
  }
  #pragma unroll
  for (int s = 0; s < 6; ++s) {
    const int half = 1 << s;
    float wx, wy;
    if (s == 0) { wx = (l & 1) ? -1.f : 1.f; wy = 0.f; }
    else {
      const int idx = (l << (5 - s)) & 63;
      wx = __shfl(Tc, idx);
      float tsv = __shfl(Ts, idx);
      wy = (DIR < 0) ? tsv : -tsv;
    }
    #pragma unroll
    for (int r = 0; r < 4; ++r) {
      float tx = __shfl_xor(v[r].x, half);
      float ty = __shfl_xor(v[r].y, half);
      const bool low = (l & half) == 0;
      float ax = low ? v[r].x : tx, ay = low ? v[r].y : ty;
      float bx = low ? tx : v[r].x, by = low ? ty : v[r].y;
      v[r].x = ax + (wx * bx - wy * by);
      v[r].y = ay + (wx * by + wy * bx);
    }
  }
  const float u2x = ux * ux - uy * uy, u2y = 2.f * ux * uy;
  const float u3x = u2x * ux - u2y * uy, u3y = u2x * uy + u2y * ux;
  float2 t0 = v[0];
  float2 t1 = mkf2(v[1].x * ux - v[1].y * uy, v[1].x * uy + v[1].y * ux);
  float2 t2 = mkf2(v[2].x * u2x - v[2].y * u2y, v[2].x * u2y + v[2].y * u2x);
  float2 t3 = mkf2(v[3].x * u3x - v[3].y * u3y, v[3].x * u3y + v[3].y * u3x);
  float2 p02 = mkf2(t0.x + t2.x, t0.y + t2.y), m02 = mkf2(t0.x - t2.x, t0.y - t2.y);
  float2 p13 = mkf2(t1.x + t3.x, t1.y + t3.y), m13 = mkf2(t1.x - t3.x, t1.y - t3.y);
  v[0] = mkf2(p02.x + p13.x, p02.y + p13.y);
  v[2] = mkf2(p02.x - p13.x, p02.y - p13.y);
  if (DIR < 0) {
    v[1] = mkf2(m02.x + m13.y, m02.y - m13.x);   // m02 - i*m13
    v[3] = mkf2(m02.x - m13.y, m02.y + m13.x);   // m02 + i*m13
  } else {
    v[1] = mkf2(m02.x - m13.y, m02.y + m13.x);
    v[3] = mkf2(m02.x + m13.y, m02.y - m13.x);
  }
}

// ---------------- kernel A: impulse spectra (one wave per step j) -----------
__global__ __launch_bounds__(256) void kernA(const float* __restrict__ env,
                                             const float* __restrict__ noise,
                                             const float* __restrict__ tf_re,
                                             const float* __restrict__ etf_re,
                                             const float* __restrict__ etf_im,
                                             float* __restrict__ IMP,
                                             float* __restrict__ T256,
                                             float* __restrict__ I256) {
  const int l = threadIdx.x & 63;
  const int j = blockIdx.x * 4 + (threadIdx.x >> 6);
  float* rowf = IMP + (size_t)j * ROWF;
  float2* row = (float2*)rowf;
  if (j >= N_STEPS) {
    if (j == N_STEPS) {                  // row N_STEPS = 0 (tail prefetch reads it)
      #pragma unroll
      for (int r = 0; r < 4; ++r) row[64 * r + l] = mkf2(0.f, 0.f);
      if (l == 0) { row[256] = mkf2(0.f, 0.f); I256[N_STEPS] = 0.f; }
    }
    return;
  }
  const int K = 32 * j + l;
  float e0 = env[K];                e0 *= e0;
  float em = env[max(K - 1, 0)];    em *= em;
  float ep = env[min(K + 1, ENV_N - 1)]; ep *= ep;
  float sm[8];
  #pragma unroll
  for (int u = 0; u < 8; ++u) {
    float val;
    if (u < 4) {
      float fr = 0.5625f + 0.125f * (float)u;
      val = em * (1.f - fr) + e0 * fr;
      if (K == 0) val = e0;              // ref clamps coords at 0
    } else {
      float fr = 0.0625f + 0.125f * (float)(u - 4);
      val = e0 * (1.f - fr) + ep * fr;
    }
    sm[u] = val;
  }
  const float4* np = (const float4*)(noise + (size_t)j * 512 + 8 * l);
  float4 n0 = np[0], n1 = np[1];
  float nn[8] = {n0.x, n0.y, n0.z, n0.w, n1.x, n1.y, n1.z, n1.w};
  float2 v[4];
  #pragma unroll
  for (int r = 0; r < 4; ++r)
    v[r] = mkf2(nn[2 * r] * sm[2 * r], nn[2 * r + 1] * sm[2 * r + 1]);

  float ca, sa; sincosf(-0.01227184630308513f * (float)l, &sa, &ca);
  const float ux = ca * ca - sa * sa, uy = 2.f * ca * sa;
  float Tc, Ts; sincosf(-0.09817477042468103f * (float)l, &Ts, &Tc);

  waveFFT256<-1>(v, l, Tc, Ts, ux, uy);  // v[r] = Z[64r + l]

  float2 Zc[4];
  const int pidx = (64 - l) & 63;
  #pragma unroll
  for (int r = 0; r < 4; ++r) {
    Zc[r].x = __shfl(v[3 - r].x, pidx);
    Zc[r].y = __shfl(v[3 - r].y, pidx);
  }
  float2 z0lane = v[0];
  if (l == 0) { Zc[0] = v[0]; Zc[1] = v[3]; Zc[2] = v[2]; Zc[3] = v[1]; }
  constexpr float crA[4] = {1.f, 0.7071067811865476f, 0.f, -0.7071067811865476f};
  constexpr float srA[4] = {0.f, -0.7071067811865476f, -1.f, -0.7071067811865476f};
  const float FS = 0.04419417382415922f;                  // 1/sqrt(512)
  #pragma unroll
  for (int r = 0; r < 4; ++r) {
    float Ex = 0.5f * (v[r].x + Zc[r].x), Ey = 0.5f * (v[r].y - Zc[r].y);
    float Dx = v[r].x - Zc[r].x,          Dy = v[r].y + Zc[r].y;
    float Ox = 0.5f * Dy, Oy = -0.5f * Dx;
    float c  = crA[r] * ca - srA[r] * sa;                 // e^{-i pi k/256}
    float sn = crA[r] * sa + srA[r] * ca;
    float Wx = (Ex + (c * Ox - sn * Oy)) * FS;
    float Wy = (Ey + (c * Oy + sn * Ox)) * FS;
    int k = 64 * r + l;
    float er = etf_re[k], ei = etf_im[k];
    float Px = Wx * er - Wy * ei;
    float Py = Wx * ei + Wy * er;
    if (k == 0) Py = 0.f;                // irfft drops Im at DC
    row[k] = mkf2(Px, Py);
  }
  if (l == 0) {
    float W256 = (z0lane.x - z0lane.y) * FS;
    float imp256 = W256 * etf_re[256];
    row[256] = mkf2(imp256, 0.f);
    I256[j] = imp256;
    T256[j] = tf_re[(size_t)j * 257 + 256];
  }
}

// ---------------- kernel B: chunked frequency-domain scan, 8-deep pipeline --
struct StepBuf {
  f4a tr, ti;
  float4 ia, ib;
};

__device__ inline void loadStep(StepBuf& b, int i, int l,
                                const float* __restrict__ tf_re,
                                const float* __restrict__ tf_im,
                                const float* __restrict__ IMP) {
  const size_t tb = (size_t)i * 257 + 4 * l;
  b.tr = *(const f4a*)(tf_re + tb);
  b.ti = *(const f4a*)(tf_im + tb);
  const float4* r4 = (const float4*)(IMP + (size_t)(i + 1) * ROWF);
  b.ia = r4[2 * l];
  b.ib = r4[2 * l + 1];
}

__device__ inline void doStep(int i, int j0, const StepBuf& b, int l,
                              float tfr256, float imp256,
                              float2& s0, float2& s1, float2& s2, float2& s3,
                              float& s256, float* __restrict__ S) {
  float2 y0, y1, y2, y3;
  y0.x = s0.x * b.tr[0] - s0.y * b.ti[0];  y0.y = s0.x * b.ti[0] + s0.y * b.tr[0];
  y1.x = s1.x * b.tr[1] - s1.y * b.ti[1];  y1.y = s1.x * b.ti[1] + s1.y * b.tr[1];
  y2.x = s2.x * b.tr[2] - s2.y * b.ti[2];  y2.y = s2.x * b.ti[2] + s2.y * b.tr[2];
  y3.x = s3.x * b.tr[3] - s3.y * b.ti[3];  y3.y = s3.x * b.ti[3] + s3.y * b.tr[3];
  if (l == 0) y0.y = 0.f;              // drop Im at DC (irfft semantics)
  float Y256 = tfr256 * s256;          // Nyquist, real (Im dropped)
  float phx = __shfl_up(y3.x, 1), phy = __shfl_up(y3.y, 1);
  float nlx = __shfl_down(y0.x, 1), nly = __shfl_down(y0.y, 1);
  float2 p0 = (l == 0)  ? mkf2(y1.x, -y1.y) : mkf2(phx, phy);  // Y_{-1} = conj(Y_1)
  float2 n3 = (l == 63) ? mkf2(Y256, 0.f)   : mkf2(nlx, nly);  // Y_256 (real)
  float y255x = __shfl(y3.x, 63);
  const float A = 0.54f, Bc = 0.23f;
  float2 c0, c1, c2, c3;
  c0.x = A * y0.x - Bc * (p0.x + y1.x);  c0.y = A * y0.y - Bc * (p0.y + y1.y);
  c1.x = A * y1.x - Bc * (y0.x + y2.x);  c1.y = A * y1.y - Bc * (y0.y + y2.y);
  c2.x = A * y2.x - Bc * (y1.x + y3.x);  c2.y = A * y2.y - Bc * (y1.y + y3.y);
  c3.x = A * y3.x - Bc * (y2.x + n3.x);  c3.y = A * y3.y - Bc * (y2.y + n3.y);
  float C256 = A * Y256 - 0.46f * y255x;
  s0.x = c0.x + b.ia.x;  s0.y = c0.y + b.ia.y;
  s1.x = c1.x + b.ia.z;  s1.y = c1.y + b.ia.w;
  s2.x = c2.x + b.ib.x;  s2.y = c2.y + b.ib.y;
  s3.x = c3.x + b.ib.z;  s3.y = c3.y + b.ib.w;
  s256 = C256 + imp256;
  if (i >= j0) {
    float4* o4 = (float4*)(S + (size_t)(i + 1) * ROWF);
    o4[2 * l]     = make_float4(s0.x, s0.y, s1.x, s1.y);
    o4[2 * l + 1] = make_float4(s2.x, s2.y, s3.x, s3.y);
    if (l == 0) {
      S[(size_t)(i + 1) * ROWF + 512] = s256;
      S[(size_t)(i + 1) * ROWF + 513] = 0.f;
    }
  }
}

__global__ __launch_bounds__(64, 1) void kernB(const float* __restrict__ tf_re,
                                               const float* __restrict__ tf_im,
                                               const float* __restrict__ IMP,
                                               const float* __restrict__ T256,
                                               const float* __restrict__ I256,
                                               float* __restrict__ S) {
  const int c = blockIdx.x, l = threadIdx.x;
  const int j0 = c * LCH;
  const int jend = min(j0 + LCH, N_STEPS);
  const int w0 = max(0, j0 - KWARM);     // nsteps = 8 (c==0) or 24 -> both %8==0
  const int last = jend - 1;
  // per-lane preload of the wave-uniform bin-256 series (vector loads)
  const float t256v = T256[min(w0 + l, N_STEPS - 1)];      // lane m <-> step w0+m
  const float i256v = I256[min(w0 + 1 + l, N_STEPS)];
  float2 s0 = mkf2(0.f, 0.f), s1 = s0, s2 = s0, s3 = s0;
  float s256 = 0.f;
  if (c == 0) {                          // exact init: S_0 = IMP_0; store row 0
    const float4* r4 = (const float4*)IMP;
    float4 a = r4[2 * l], bb = r4[2 * l + 1];
    s0 = mkf2(a.x, a.y);  s1 = mkf2(a.z, a.w);
    s2 = mkf2(bb.x, bb.y); s3 = mkf2(bb.z, bb.w);
    s256 = IMP[512];
    float4* o4 = (float4*)S;
    o4[2 * l] = a; o4[2 * l + 1] = bb;
    if (l == 0) { S[512] = s256; S[513] = 0.f; }
  }
  StepBuf b0, b1, b2, b3, b4, b5, b6, b7;
  loadStep(b0, w0 + 0, l, tf_re, tf_im, IMP);
  loadStep(b1, w0 + 1, l, tf_re, tf_im, IMP);
  loadStep(b2, w0 + 2, l, tf_re, tf_im, IMP);
  loadStep(b3, w0 + 3, l, tf_re, tf_im, IMP);
  loadStep(b4, w0 + 4, l, tf_re, tf_im, IMP);
  loadStep(b5, w0 + 5, l, tf_re, tf_im, IMP);
  loadStep(b6, w0 + 6, l, tf_re, tf_im, IMP);
  loadStep(b7, w0 + 7, l, tf_re, tf_im, IMP);
  int i = w0;
  #define STEP8(BUF) { \
    const int m = i - w0; \
    const float tfr_ = __shfl(t256v, m); \
    const float im2_ = __shfl(i256v, m); \
    doStep(i, j0, BUF, l, tfr_, im2_, s0, s1, s2, s3, s256, S); \
    int nx = i + 8; nx = (nx > last) ? last : nx; \
    loadStep(BUF, nx, l, tf_re, tf_im, IMP); \
    ++i; }
  while (i < jend) {
    STEP8(b0) STEP8(b1) STEP8(b2) STEP8(b3)
    STEP8(b4) STEP8(b5) STEP8(b6) STEP8(b7)
  }
  #undef STEP8
}

// ---------------- kernel C: irfft + overlap-add, fused ----------------------
__global__ __launch_bounds__(576) void kernC(const float* __restrict__ S,
                                             float* __restrict__ out) {
  const int l = threadIdx.x & 63;
  const int w = threadIdx.x >> 6;                      // 0..8
  const int b = blockIdx.x;                            // 0..1279
  const int r = 8 * b - 1 + w;                         // -1 .. 10239
  __shared__ float2 ybuf[9][256];
  if (r < 0) {
    #pragma unroll
    for (int rr = 0; rr < 4; ++rr) ybuf[0][64 * rr + l] = mkf2(0.f, 0.f);
  } else {
    const float2* row = (const float2*)(S + (size_t)r * ROWF);
    const float4* r4 = (const float4*)row;
    float4 a = r4[2 * l], bb = r4[2 * l + 1];
    float2 W[4] = {mkf2(a.x, a.y), mkf2(a.z, a.w), mkf2(bb.x, bb.y), mkf2(bb.z, bb.w)};
    float w256 = row[256].x;
    float2 Wm[4];
    const int pidx = (64 - l) & 63;
    Wm[0].x = __shfl(W[0].x, pidx);
    Wm[0].y = __shfl(W[0].y, pidx);
    if (l == 0) Wm[0] = mkf2(w256, 0.f);
    Wm[1].x = __shfl_xor(W[3].x, 63);  Wm[1].y = __shfl_xor(W[3].y, 63);
    Wm[2].x = __shfl_xor(W[2].x, 63);  Wm[2].y = __shfl_xor(W[2].y, 63);
    Wm[3].x = __shfl_xor(W[1].x, 63);  Wm[3].y = __shfl_xor(W[1].y, 63);
    float cu, su; sincosf(0.02454369260617026f * (float)l, &su, &cu);
    const float cl = cu * cu - su * su, sl_ = 2.f * cu * su;
    float Tc, Ts; sincosf(-0.09817477042468103f * (float)l, &Ts, &Tc);
    constexpr float crC[4] = {1.f, 0.9999247018391445f, 0.9996988186962042f, 0.9993223845883495f};
    constexpr float srC[4] = {0.f, 0.0122715382857199f, 0.0245412285229123f, 0.0368072229413588f};
    float2 v[4];
    #pragma unroll
    for (int rr = 0; rr < 4; ++rr) {
      float Ex = 0.5f * (W[rr].x + Wm[rr].x), Ey = 0.5f * (W[rr].y - Wm[rr].y);
      float Dx = W[rr].x - Wm[rr].x,          Dy = W[rr].y + Wm[rr].y;
      float c  = cl * crC[rr] - sl_ * srC[rr];
      float sn = cl * srC[rr] + sl_ * crC[rr];
      float Ox = 0.5f * (c * Dx - sn * Dy);
      float Oy = 0.5f * (c * Dy + sn * Dx);
      v[rr] = mkf2(Ex - Oy, Ey + Ox);
    }
    waveFFT256<+1>(v, l, Tc, Ts, cu, su);
    const float ISC = 0.08838834764831845f;  // sqrt(512)/256
    #pragma unroll
    for (int rr = 0; rr < 4; ++rr)
      ybuf[w][64 * rr + l] = mkf2(v[rr].x * ISC, v[rr].y * ISC);
  }
  __syncthreads();
  float2* out2 = (float2*)out;
  const size_t base = (size_t)b * 1024;
  for (int idx = threadIdx.x; idx < 1024; idx += 576) {
    const int k = idx >> 7, t2 = idx & 127;
    float2 a = ybuf[k + 1][t2];
    float2 p = ybuf[k][128 + t2];
    out2[base + idx] = mkf2(a.x + p.x, a.y + p.y);
  }
}

// ---------------- launch ----------------
extern "C" void kernel_launch(void* const* d_in, const int* in_sizes, int n_in,
                              void* d_out, int out_size, void* d_ws, size_t ws_size,
                              hipStream_t stream) {
  const float* env    = (const float*)d_in[1];
  const float* tf_re  = (const float*)d_in[2];
  const float* tf_im  = (const float*)d_in[3];
  const float* etf_re = (const float*)d_in[4];
  const float* etf_im = (const float*)d_in[5];
  const float* noise  = (const float*)d_in[6];
  float* out = (float*)d_out;

  float* wsf = (float*)d_ws;
  float* IMP  = wsf;                                   // (N_STEPS+1) x ROWF
  float* S    = wsf + (size_t)(N_STEPS + 1) * ROWF;    // (N_STEPS+1) x ROWF
  float* T256 = wsf + (size_t)2 * (N_STEPS + 1) * ROWF;      // N_STEPS floats
  float* I256 = T256 + N_STEPS;                              // N_STEPS+1 floats
  // ws use: 2 * 10241 * 2112 B + ~82 KB ~= 43.4 MB

  kernA<<<(N_STEPS / 4) + 1, 256, 0, stream>>>(env, noise, tf_re, etf_re, etf_im,
                                               IMP, T256, I256);
  kernB<<<N_STEPS / LCH, 64, 0, stream>>>(tf_re, tf_im, IMP, T256, I256, S);
  kernC<<<N_STEPS / 8, 576, 0, stream>>>(S, out);
}

// Round 13
// 57.504 us; speedup vs baseline: 1.4216x; 1.0643x over previous
//
#include <hip/hip_runtime.h>
#include <math.h>

#define N_STEPS 10240
#define ROWF2 264          // float2 slots per spectral row (257 used, padded)
#define ROWF  (ROWF2*2)    // floats per row = 528
#define ENV_N 327744       // N_FRAMES*32
#define LCH 16             // scan chunk length (640 chunks)
#define KWARM 16           // warm-up steps (contraction 0.283^16 ~ 1.6e-9 rel)

typedef float f4a __attribute__((ext_vector_type(4), aligned(4)));

__device__ inline float2 mkf2(float x, float y) { return make_float2(x, y); }

// ---------------- wave-level complex FFT-256: 64 lanes, 4 float2 regs -------
template<int DIR>
__device__ inline void waveFFT256(float2 v[4], const int l,
                                  const float Tc, const float Ts,
                                  const float ux, const float uy) {
  const int rb = (int)(__brev((unsigned)l) >> 26);
  #pragma unroll
  for (int r = 0; r < 4; ++r) {
    v[r].x = __shfl(v[r].x, rb);
    v[r].y = __shfl(v[r].y, rb);
  }
  #pragma unroll
  for (int s = 0; s < 6; ++s) {
    const int half = 1 << s;
    float wx, wy;
    if (s == 0) { wx = (l & 1) ? -1.f : 1.f; wy = 0.f; }
    else {
      const int idx = (l << (5 - s)) & 63;
      wx = __shfl(Tc, idx);
      float tsv = __shfl(Ts, idx);
      wy = (DIR < 0) ? tsv : -tsv;
    }
    #pragma unroll
    for (int r = 0; r < 4; ++r) {
      float tx = __shfl_xor(v[r].x, half);
      float ty = __shfl_xor(v[r].y, half);
      const bool low = (l & half) == 0;
      float ax = low ? v[r].x : tx, ay = low ? v[r].y : ty;
      float bx = low ? tx : v[r].x, by = low ? ty : v[r].y;
      v[r].x = ax + (wx * bx - wy * by);
      v[r].y = ay + (wx * by + wy * bx);
    }
  }
  const float u2x = ux * ux - uy * uy, u2y = 2.f * ux * uy;
  const float u3x = u2x * ux - u2y * uy, u3y = u2x * uy + u2y * ux;
  float2 t0 = v[0];
  float2 t1 = mkf2(v[1].x * ux - v[1].y * uy, v[1].x * uy + v[1].y * ux);
  float2 t2 = mkf2(v[2].x * u2x - v[2].y * u2y, v[2].x * u2y + v[2].y * u2x);
  float2 t3 = mkf2(v[3].x * u3x - v[3].y * u3y, v[3].x * u3y + v[3].y * u3x);
  float2 p02 = mkf2(t0.x + t2.x, t0.y + t2.y), m02 = mkf2(t0.x - t2.x, t0.y - t2.y);
  float2 p13 = mkf2(t1.x + t3.x, t1.y + t3.y), m13 = mkf2(t1.x - t3.x, t1.y - t3.y);
  v[0] = mkf2(p02.x + p13.x, p02.y + p13.y);
  v[2] = mkf2(p02.x - p13.x, p02.y - p13.y);
  if (DIR < 0) {
    v[1] = mkf2(m02.x + m13.y, m02.y - m13.x);   // m02 - i*m13
    v[3] = mkf2(m02.x - m13.y, m02.y + m13.x);   // m02 + i*m13
  } else {
    v[1] = mkf2(m02.x - m13.y, m02.y + m13.x);
    v[3] = mkf2(m02.x + m13.y, m02.y - m13.x);
  }
}

// ---------------- kernel A: impulse spectra (one wave per step j) -----------
__global__ __launch_bounds__(256) void kernA(const float* __restrict__ env,
                                             const float* __restrict__ noise,
                                             const float* __restrict__ tf_re,
                                             const float* __restrict__ etf_re,
                                             const float* __restrict__ etf_im,
                                             float* __restrict__ IMP,
                                             float* __restrict__ T256,
                                             float* __restrict__ I256) {
  const int l = threadIdx.x & 63;
  const int j = blockIdx.x * 4 + (threadIdx.x >> 6);
  float* rowf = IMP + (size_t)j * ROWF;
  float2* row = (float2*)rowf;
  if (j >= N_STEPS) {
    if (j == N_STEPS) {                  // row N_STEPS = 0 (tail prefetch reads it)
      #pragma unroll
      for (int r = 0; r < 4; ++r) row[64 * r + l] = mkf2(0.f, 0.f);
      if (l == 0) { row[256] = mkf2(0.f, 0.f); I256[N_STEPS] = 0.f; }
    }
    return;
  }
  const int K = 32 * j + l;
  float e0 = env[K];                e0 *= e0;
  float em = env[max(K - 1, 0)];    em *= em;
  float ep = env[min(K + 1, ENV_N - 1)]; ep *= ep;
  float sm[8];
  #pragma unroll
  for (int u = 0; u < 8; ++u) {
    float val;
    if (u < 4) {
      float fr = 0.5625f + 0.125f * (float)u;
      val = em * (1.f - fr) + e0 * fr;
      if (K == 0) val = e0;              // ref clamps coords at 0
    } else {
      float fr = 0.0625f + 0.125f * (float)(u - 4);
      val = e0 * (1.f - fr) + ep * fr;
    }
    sm[u] = val;
  }
  const float4* np = (const float4*)(noise + (size_t)j * 512 + 8 * l);
  float4 n0 = np[0], n1 = np[1];
  float nn[8] = {n0.x, n0.y, n0.z, n0.w, n1.x, n1.y, n1.z, n1.w};
  float2 v[4];
  #pragma unroll
  for (int r = 0; r < 4; ++r)
    v[r] = mkf2(nn[2 * r] * sm[2 * r], nn[2 * r + 1] * sm[2 * r + 1]);

  float ca, sa; sincosf(-0.01227184630308513f * (float)l, &sa, &ca);
  const float ux = ca * ca - sa * sa, uy = 2.f * ca * sa;
  float Tc, Ts; sincosf(-0.09817477042468103f * (float)l, &Ts, &Tc);

  waveFFT256<-1>(v, l, Tc, Ts, ux, uy);  // v[r] = Z[64r + l]

  float2 Zc[4];
  const int pidx = (64 - l) & 63;
  #pragma unroll
  for (int r = 0; r < 4; ++r) {
    Zc[r].x = __shfl(v[3 - r].x, pidx);
    Zc[r].y = __shfl(v[3 - r].y, pidx);
  }
  float2 z0lane = v[0];
  if (l == 0) { Zc[0] = v[0]; Zc[1] = v[3]; Zc[2] = v[2]; Zc[3] = v[1]; }
  constexpr float crA[4] = {1.f, 0.7071067811865476f, 0.f, -0.7071067811865476f};
  constexpr float srA[4] = {0.f, -0.7071067811865476f, -1.f, -0.7071067811865476f};
  const float FS = 0.04419417382415922f;                  // 1/sqrt(512)
  #pragma unroll
  for (int r = 0; r < 4; ++r) {
    float Ex = 0.5f * (v[r].x + Zc[r].x), Ey = 0.5f * (v[r].y - Zc[r].y);
    float Dx = v[r].x - Zc[r].x,          Dy = v[r].y + Zc[r].y;
    float Ox = 0.5f * Dy, Oy = -0.5f * Dx;
    float c  = crA[r] * ca - srA[r] * sa;                 // e^{-i pi k/256}
    float sn = crA[r] * sa + srA[r] * ca;
    float Wx = (Ex + (c * Ox - sn * Oy)) * FS;
    float Wy = (Ey + (c * Oy + sn * Ox)) * FS;
    int k = 64 * r + l;
    float er = etf_re[k], ei = etf_im[k];
    float Px = Wx * er - Wy * ei;
    float Py = Wx * ei + Wy * er;
    if (k == 0) Py = 0.f;                // irfft drops Im at DC
    row[k] = mkf2(Px, Py);
  }
  if (l == 0) {
    float W256 = (z0lane.x - z0lane.y) * FS;
    float imp256 = W256 * etf_re[256];
    row[256] = mkf2(imp256, 0.f);
    I256[j] = imp256;
    T256[j] = tf_re[(size_t)j * 257 + 256];
  }
}

// ---------------- kernel B: 4-wave scan, 1 bin per lane ---------------------
// Block = 256 threads; bin = tid. conv3 neighbor exchange: shfl within wave +
// LDS edge buffer at wave boundaries; ONE __syncthreads per step (dbl-buffered).
// Lane 255 owns both bin 255 and the (real) Nyquist bin 256 state.
struct StepBuf { float tr, ti; float2 im; };

__device__ inline void loadStep(StepBuf& b, int i, int bin,
                                const float* __restrict__ tf_re,
                                const float* __restrict__ tf_im,
                                const float* __restrict__ IMP) {
  b.tr = tf_re[(size_t)i * 257 + bin];
  b.ti = tf_im[(size_t)i * 257 + bin];
  b.im = ((const float2*)(IMP + (size_t)(i + 1) * ROWF))[bin];
}

__global__ __launch_bounds__(256, 1) void kernB(const float* __restrict__ tf_re,
                                                const float* __restrict__ tf_im,
                                                const float* __restrict__ IMP,
                                                const float* __restrict__ T256,
                                                const float* __restrict__ I256,
                                                float* __restrict__ S) {
  const int c = blockIdx.x;
  const int tid = threadIdx.x;
  const int lane = tid & 63;
  const int w = tid >> 6;                // 0..3
  const int bin = tid;                   // 0..255
  const bool nyq = (tid == 255);
  const int j0 = c * LCH;
  const int jend = j0 + LCH;
  const int w0 = (c > 0) ? (j0 - KWARM) : 0;
  const int last = jend - 1;

  __shared__ float2 edge[2][4][2];       // [parity][wave][0:lane0 y, 1:lane63 y]

  // per-lane preload of the wave-uniform bin-256 series (all waves load same)
  const float t256v = T256[min(w0 + lane, N_STEPS - 1)];
  const float i256v = I256[min(w0 + 1 + lane, N_STEPS)];

  float2 sb = mkf2(0.f, 0.f);
  float s256 = 0.f;

  if (c == 0) {                          // exact init: S_0 = IMP_0; store row 0
    sb = ((const float2*)IMP)[bin];
    ((float2*)S)[bin] = sb;
    if (nyq) { s256 = IMP[512]; S[512] = s256; S[513] = 0.f; }
  }

  StepBuf b0, b1, b2, b3, b4, b5, b6, b7;
  loadStep(b0, w0 + 0, bin, tf_re, tf_im, IMP);
  loadStep(b1, w0 + 1, bin, tf_re, tf_im, IMP);
  loadStep(b2, w0 + 2, bin, tf_re, tf_im, IMP);
  loadStep(b3, w0 + 3, bin, tf_re, tf_im, IMP);
  loadStep(b4, w0 + 4, bin, tf_re, tf_im, IMP);
  loadStep(b5, w0 + 5, bin, tf_re, tf_im, IMP);
  loadStep(b6, w0 + 6, bin, tf_re, tf_im, IMP);
  loadStep(b7, w0 + 7, bin, tf_re, tf_im, IMP);

  int i = w0;
  #define STEP(BUF) { \
    const int m = i - w0; \
    const float tfr_ = __shfl(t256v, m);     /* uniform broadcasts, all lanes */ \
    const float im2_ = __shfl(i256v, m); \
    float2 y; \
    y.x = sb.x * BUF.tr - sb.y * BUF.ti; \
    y.y = sb.x * BUF.ti + sb.y * BUF.tr; \
    if (bin == 0) y.y = 0.f;                 /* drop Im at DC */ \
    const float Y256 = tfr_ * s256;          /* meaningful on lane 255 only */ \
    const int p = i & 1; \
    if (lane == 0)  edge[p][w][0] = y; \
    if (lane == 63) edge[p][w][1] = y; \
    __syncthreads(); \
    float2 yp, ym; \
    yp.x = __shfl_down(y.x, 1);  yp.y = __shfl_down(y.y, 1); \
    ym.x = __shfl_up(y.x, 1);    ym.y = __shfl_up(y.y, 1); \
    if (lane == 63 && w < 3) yp = edge[p][w + 1][0]; \
    if (lane == 0  && w > 0) ym = edge[p][w - 1][1]; \
    if (bin == 0) ym = mkf2(yp.x, -yp.y);    /* Y_{-1} = conj(Y_1) */ \
    if (nyq)      yp = mkf2(Y256, 0.f);      /* Y_256 (real), lane-local */ \
    float2 cc; \
    cc.x = 0.54f * y.x - 0.23f * (ym.x + yp.x); \
    cc.y = 0.54f * y.y - 0.23f * (ym.y + yp.y); \
    sb.x = cc.x + BUF.im.x; \
    sb.y = cc.y + BUF.im.y; \
    if (nyq) s256 = 0.54f * Y256 - 0.46f * y.x + im2_;  /* y.x = Re(y255) */ \
    if (i >= j0) { \
      ((float2*)(S + (size_t)(i + 1) * ROWF))[bin] = sb; \
      if (nyq) { \
        S[(size_t)(i + 1) * ROWF + 512] = s256; \
        S[(size_t)(i + 1) * ROWF + 513] = 0.f; \
      } \
    } \
    { int nx = i + 8; nx = (nx > last) ? last : nx; loadStep(BUF, nx, bin, tf_re, tf_im, IMP); } \
    ++i; }

  while (i < jend) {
    STEP(b0) STEP(b1) STEP(b2) STEP(b3)
    STEP(b4) STEP(b5) STEP(b6) STEP(b7)
  }
  #undef STEP
}

// ---------------- kernel C: irfft + overlap-add, fused ----------------------
__global__ __launch_bounds__(576) void kernC(const float* __restrict__ S,
                                             float* __restrict__ out) {
  const int l = threadIdx.x & 63;
  const int w = threadIdx.x >> 6;                      // 0..8
  const int b = blockIdx.x;                            // 0..1279
  const int r = 8 * b - 1 + w;                         // -1 .. 10239
  __shared__ float2 ybuf[9][256];
  if (r < 0) {
    #pragma unroll
    for (int rr = 0; rr < 4; ++rr) ybuf[0][64 * rr + l] = mkf2(0.f, 0.f);
  } else {
    const float2* row = (const float2*)(S + (size_t)r * ROWF);
    const float4* r4 = (const float4*)row;
    float4 a = r4[2 * l], bb = r4[2 * l + 1];
    float2 W[4] = {mkf2(a.x, a.y), mkf2(a.z, a.w), mkf2(bb.x, bb.y), mkf2(bb.z, bb.w)};
    float w256 = row[256].x;
    float2 Wm[4];
    const int pidx = (64 - l) & 63;
    Wm[0].x = __shfl(W[0].x, pidx);
    Wm[0].y = __shfl(W[0].y, pidx);
    if (l == 0) Wm[0] = mkf2(w256, 0.f);
    Wm[1].x = __shfl_xor(W[3].x, 63);  Wm[1].y = __shfl_xor(W[3].y, 63);
    Wm[2].x = __shfl_xor(W[2].x, 63);  Wm[2].y = __shfl_xor(W[2].y, 63);
    Wm[3].x = __shfl_xor(W[1].x, 63);  Wm[3].y = __shfl_xor(W[1].y, 63);
    float cu, su; sincosf(0.02454369260617026f * (float)l, &su, &cu);
    const float cl = cu * cu - su * su, sl_ = 2.f * cu * su;
    float Tc, Ts; sincosf(-0.09817477042468103f * (float)l, &Ts, &Tc);
    constexpr float crC[4] = {1.f, 0.9999247018391445f, 0.9996988186962042f, 0.9993223845883495f};
    constexpr float srC[4] = {0.f, 0.0122715382857199f, 0.0245412285229123f, 0.0368072229413588f};
    float2 v[4];
    #pragma unroll
    for (int rr = 0; rr < 4; ++rr) {
      float Ex = 0.5f * (W[rr].x + Wm[rr].x), Ey = 0.5f * (W[rr].y - Wm[rr].y);
      float Dx = W[rr].x - Wm[rr].x,          Dy = W[rr].y + Wm[rr].y;
      float c  = cl * crC[rr] - sl_ * srC[rr];
      float sn = cl * srC[rr] + sl_ * crC[rr];
      float Ox = 0.5f * (c * Dx - sn * Dy);
      float Oy = 0.5f * (c * Dy + sn * Dx);
      v[rr] = mkf2(Ex - Oy, Ey + Ox);
    }
    waveFFT256<+1>(v, l, Tc, Ts, cu, su);
    const float ISC = 0.08838834764831845f;  // sqrt(512)/256
    #pragma unroll
    for (int rr = 0; rr < 4; ++rr)
      ybuf[w][64 * rr + l] = mkf2(v[rr].x * ISC, v[rr].y * ISC);
  }
  __syncthreads();
  float2* out2 = (float2*)out;
  const size_t base = (size_t)b * 1024;
  for (int idx = threadIdx.x; idx < 1024; idx += 576) {
    const int k = idx >> 7, t2 = idx & 127;
    float2 a = ybuf[k + 1][t2];
    float2 p = ybuf[k][128 + t2];
    out2[base + idx] = mkf2(a.x + p.x, a.y + p.y);
  }
}

// ---------------- launch ----------------
extern "C" void kernel_launch(void* const* d_in, const int* in_sizes, int n_in,
                              void* d_out, int out_size, void* d_ws, size_t ws_size,
                              hipStream_t stream) {
  const float* env    = (const float*)d_in[1];
  const float* tf_re  = (const float*)d_in[2];
  const float* tf_im  = (const float*)d_in[3];
  const float* etf_re = (const float*)d_in[4];
  const float* etf_im = (const float*)d_in[5];
  const float* noise  = (const float*)d_in[6];
  float* out = (float*)d_out;

  float* wsf = (float*)d_ws;
  float* IMP  = wsf;                                   // (N_STEPS+1) x ROWF
  float* S    = wsf + (size_t)(N_STEPS + 1) * ROWF;    // (N_STEPS+1) x ROWF
  float* T256 = wsf + (size_t)2 * (N_STEPS + 1) * ROWF;      // N_STEPS floats
  float* I256 = T256 + N_STEPS;                              // N_STEPS+1 floats
  // ws use: 2 * 10241 * 2112 B + ~82 KB ~= 43.4 MB

  kernA<<<(N_STEPS / 4) + 1, 256, 0, stream>>>(env, noise, tf_re, etf_re, etf_im,
                                               IMP, T256, I256);
  kernB<<<N_STEPS / LCH, 256, 0, stream>>>(tf_re, tf_im, IMP, T256, I256, S);
  kernC<<<N_STEPS / 8, 576, 0, stream>>>(S, out);
}

// Round 14
// 49.255 us; speedup vs baseline: 1.6597x; 1.1675x over previous
//
#include <hip/hip_runtime.h>
#include <math.h>

#define N_STEPS 10240
#define ROWF2 264          // float2 slots per IMP row (257 used, padded)
#define ROWF  (ROWF2*2)    // floats per IMP row = 528 (2112 B)
#define ENV_N 327744       // N_FRAMES*32
#define LCH 16             // chunk length (640 chunks)

typedef float f4a __attribute__((ext_vector_type(4), aligned(4)));

__device__ inline float2 mkf2(float x, float y) { return make_float2(x, y); }

// ---------------- wave-level complex FFT-256: 64 lanes, 4 float2 regs -------
template<int DIR>
__device__ inline void waveFFT256(float2 v[4], const int l,
                                  const float Tc, const float Ts,
                                  const float ux, const float uy) {
  const int rb = (int)(__brev((unsigned)l) >> 26);
  #pragma unroll
  for (int r = 0; r < 4; ++r) {
    v[r].x = __shfl(v[r].x, rb);
    v[r].y = __shfl(v[r].y, rb);
  }
  #pragma unroll
  for (int s = 0; s < 6; ++s) {
    const int half = 1 << s;
    float wx, wy;
    if (s == 0) { wx = (l & 1) ? -1.f : 1.f; wy = 0.f; }
    else {
      const int idx = (l << (5 - s)) & 63;
      wx = __shfl(Tc, idx);
      float tsv = __shfl(Ts, idx);
      wy = (DIR < 0) ? tsv : -tsv;
    }
    #pragma unroll
    for (int r = 0; r < 4; ++r) {
      float tx = __shfl_xor(v[r].x, half);
      float ty = __shfl_xor(v[r].y, half);
      const bool low = (l & half) == 0;
      float ax = low ? v[r].x : tx, ay = low ? v[r].y : ty;
      float bx = low ? tx : v[r].x, by = low ? ty : v[r].y;
      v[r].x = ax + (wx * bx - wy * by);
      v[r].y = ay + (wx * by + wy * bx);
    }
  }
  const float u2x = ux * ux - uy * uy, u2y = 2.f * ux * uy;
  const float u3x = u2x * ux - u2y * uy, u3y = u2x * uy + u2y * ux;
  float2 t0 = v[0];
  float2 t1 = mkf2(v[1].x * ux - v[1].y * uy, v[1].x * uy + v[1].y * ux);
  float2 t2 = mkf2(v[2].x * u2x - v[2].y * u2y, v[2].x * u2y + v[2].y * u2x);
  float2 t3 = mkf2(v[3].x * u3x - v[3].y * u3y, v[3].x * u3y + v[3].y * u3x);
  float2 p02 = mkf2(t0.x + t2.x, t0.y + t2.y), m02 = mkf2(t0.x - t2.x, t0.y - t2.y);
  float2 p13 = mkf2(t1.x + t3.x, t1.y + t3.y), m13 = mkf2(t1.x - t3.x, t1.y - t3.y);
  v[0] = mkf2(p02.x + p13.x, p02.y + p13.y);
  v[2] = mkf2(p02.x - p13.x, p02.y - p13.y);
  if (DIR < 0) {
    v[1] = mkf2(m02.x + m13.y, m02.y - m13.x);
    v[3] = mkf2(m02.x - m13.y, m02.y + m13.x);
  } else {
    v[1] = mkf2(m02.x - m13.y, m02.y + m13.x);
    v[3] = mkf2(m02.x + m13.y, m02.y - m13.x);
  }
}

// ---------------- kernel A: impulse spectra (one wave per step j) -----------
__global__ __launch_bounds__(256) void kernA(const float* __restrict__ env,
                                             const float* __restrict__ noise,
                                             const float* __restrict__ tf_re,
                                             const float* __restrict__ etf_re,
                                             const float* __restrict__ etf_im,
                                             float* __restrict__ IMP,
                                             float* __restrict__ T256,
                                             float* __restrict__ I256) {
  const int l = threadIdx.x & 63;
  const int j = blockIdx.x * 4 + (threadIdx.x >> 6);
  float* rowf = IMP + (size_t)j * ROWF;
  float2* row = (float2*)rowf;
  if (j >= N_STEPS) {
    if (j == N_STEPS) {
      #pragma unroll
      for (int r = 0; r < 4; ++r) row[64 * r + l] = mkf2(0.f, 0.f);
      if (l == 0) { row[256] = mkf2(0.f, 0.f); I256[N_STEPS] = 0.f; }
    }
    return;
  }
  const int K = 32 * j + l;
  float e0 = env[K];                e0 *= e0;
  float em = env[max(K - 1, 0)];    em *= em;
  float ep = env[min(K + 1, ENV_N - 1)]; ep *= ep;
  float sm[8];
  #pragma unroll
  for (int u = 0; u < 8; ++u) {
    float val;
    if (u < 4) {
      float fr = 0.5625f + 0.125f * (float)u;
      val = em * (1.f - fr) + e0 * fr;
      if (K == 0) val = e0;              // ref clamps coords at 0
    } else {
      float fr = 0.0625f + 0.125f * (float)(u - 4);
      val = e0 * (1.f - fr) + ep * fr;
    }
    sm[u] = val;
  }
  const float4* np = (const float4*)(noise + (size_t)j * 512 + 8 * l);
  float4 n0 = np[0], n1 = np[1];
  float nn[8] = {n0.x, n0.y, n0.z, n0.w, n1.x, n1.y, n1.z, n1.w};
  float2 v[4];
  #pragma unroll
  for (int r = 0; r < 4; ++r)
    v[r] = mkf2(nn[2 * r] * sm[2 * r], nn[2 * r + 1] * sm[2 * r + 1]);

  float ca, sa; sincosf(-0.01227184630308513f * (float)l, &sa, &ca);
  const float ux = ca * ca - sa * sa, uy = 2.f * ca * sa;
  float Tc, Ts; sincosf(-0.09817477042468103f * (float)l, &Ts, &Tc);

  waveFFT256<-1>(v, l, Tc, Ts, ux, uy);  // v[r] = Z[64r + l]

  float2 Zc[4];
  const int pidx = (64 - l) & 63;
  #pragma unroll
  for (int r = 0; r < 4; ++r) {
    Zc[r].x = __shfl(v[3 - r].x, pidx);
    Zc[r].y = __shfl(v[3 - r].y, pidx);
  }
  float2 z0lane = v[0];
  if (l == 0) { Zc[0] = v[0]; Zc[1] = v[3]; Zc[2] = v[2]; Zc[3] = v[1]; }
  constexpr float crA[4] = {1.f, 0.7071067811865476f, 0.f, -0.7071067811865476f};
  constexpr float srA[4] = {0.f, -0.7071067811865476f, -1.f, -0.7071067811865476f};
  const float FS = 0.04419417382415922f;                  // 1/sqrt(512)
  #pragma unroll
  for (int r = 0; r < 4; ++r) {
    float Ex = 0.5f * (v[r].x + Zc[r].x), Ey = 0.5f * (v[r].y - Zc[r].y);
    float Dx = v[r].x - Zc[r].x,          Dy = v[r].y + Zc[r].y;
    float Ox = 0.5f * Dy, Oy = -0.5f * Dx;
    float c  = crA[r] * ca - srA[r] * sa;                 // e^{-i pi k/256}
    float sn = crA[r] * sa + srA[r] * ca;
    float Wx = (Ex + (c * Ox - sn * Oy)) * FS;
    float Wy = (Ey + (c * Oy + sn * Ox)) * FS;
    int k = 64 * r + l;
    float er = etf_re[k], ei = etf_im[k];
    float Px = Wx * er - Wy * ei;
    float Py = Wx * ei + Wy * er;
    if (k == 0) Py = 0.f;                // irfft drops Im at DC
    row[k] = mkf2(Px, Py);
  }
  if (l == 0) {
    float W256 = (z0lane.x - z0lane.y) * FS;
    float imp256 = W256 * etf_re[256];
    row[256] = mkf2(imp256, 0.f);
    I256[j] = imp256;
    T256[j] = tf_re[(size_t)j * 257 + 256];
  }
}

// ---------------- kernel BC: fused scan + iFFT + OA -------------------------
// Block = 4 waves, all running the scan REDUNDANTLY (identical data/compute;
// loads L1-broadcast). Wave w register-saves rows k == w (mod 4) (k = 0..16,
// row r = j0-1+k). Then each wave iFFTs its own rows into LDS ybuf (scan
// state layout bin 4l+r == kernC's iFFT input layout), one barrier, OA-write
// segments j0..j0+15. No S buffer, no kernC, no cross-block dependency.
struct StepBuf { f4a tr, ti; float4 ia, ib; };

__device__ inline void loadStep(StepBuf& b, int i, int l,
                                const float* __restrict__ tf_re,
                                const float* __restrict__ tf_im,
                                const float* __restrict__ IMP) {
  const size_t tb = (size_t)i * 257 + 4 * l;
  b.tr = *(const f4a*)(tf_re + tb);
  b.ti = *(const f4a*)(tf_im + tb);
  const float4* r4 = (const float4*)(IMP + (size_t)(i + 1) * ROWF);
  b.ia = r4[2 * l];
  b.ib = r4[2 * l + 1];
}

__device__ inline void doStep(const StepBuf& b, int l, float tfr256, float imp256,
                              float2& s0, float2& s1, float2& s2, float2& s3,
                              float& s256) {
  float2 y0, y1, y2, y3;
  y0.x = s0.x * b.tr[0] - s0.y * b.ti[0];  y0.y = s0.x * b.ti[0] + s0.y * b.tr[0];
  y1.x = s1.x * b.tr[1] - s1.y * b.ti[1];  y1.y = s1.x * b.ti[1] + s1.y * b.tr[1];
  y2.x = s2.x * b.tr[2] - s2.y * b.ti[2];  y2.y = s2.x * b.ti[2] + s2.y * b.tr[2];
  y3.x = s3.x * b.tr[3] - s3.y * b.ti[3];  y3.y = s3.x * b.ti[3] + s3.y * b.tr[3];
  if (l == 0) y0.y = 0.f;              // drop Im at DC (irfft semantics)
  float Y256 = tfr256 * s256;          // Nyquist, real
  float phx = __shfl_up(y3.x, 1), phy = __shfl_up(y3.y, 1);
  float nlx = __shfl_down(y0.x, 1), nly = __shfl_down(y0.y, 1);
  float2 p0 = (l == 0)  ? mkf2(y1.x, -y1.y) : mkf2(phx, phy);  // Y_{-1} = conj(Y_1)
  float2 n3 = (l == 63) ? mkf2(Y256, 0.f)   : mkf2(nlx, nly);  // Y_256 (real)
  float y255x = __shfl(y3.x, 63);
  const float A = 0.54f, Bc = 0.23f;
  float2 c0, c1, c2, c3;
  c0.x = A * y0.x - Bc * (p0.x + y1.x);  c0.y = A * y0.y - Bc * (p0.y + y1.y);
  c1.x = A * y1.x - Bc * (y0.x + y2.x);  c1.y = A * y1.y - Bc * (y0.y + y2.y);
  c2.x = A * y2.x - Bc * (y1.x + y3.x);  c2.y = A * y2.y - Bc * (y1.y + y3.y);
  c3.x = A * y3.x - Bc * (y2.x + n3.x);  c3.y = A * y3.y - Bc * (y2.y + n3.y);
  float C256 = A * Y256 - 0.46f * y255x;
  s0.x = c0.x + b.ia.x;  s0.y = c0.y + b.ia.y;
  s1.x = c1.x + b.ia.z;  s1.y = c1.y + b.ia.w;
  s2.x = c2.x + b.ib.x;  s2.y = c2.y + b.ib.y;
  s3.x = c3.x + b.ib.z;  s3.y = c3.y + b.ib.w;
  s256 = C256 + imp256;
}

__global__ __launch_bounds__(256, 2) void kernBC(const float* __restrict__ tf_re,
                                                 const float* __restrict__ tf_im,
                                                 const float* __restrict__ IMP,
                                                 const float* __restrict__ T256,
                                                 const float* __restrict__ I256,
                                                 float* __restrict__ out) {
  const int c = blockIdx.x, tid = threadIdx.x;
  const int l = tid & 63, w = tid >> 6;
  const int j0 = c * LCH;
  const int w0 = (c > 0) ? (j0 - 9) : 0;       // 7 warm steps before first saved row
  const int lastStep = (c > 0) ? (j0 + 14) : 15;

  __shared__ float2 ybuf[17][256];             // 34.8 KB

  float t256v = T256[min(w0 + l, N_STEPS - 1)];     // lane m <-> step w0+m
  float i256v = I256[min(w0 + 1 + l, N_STEPS)];

  float2 s0 = mkf2(0.f, 0.f), s1 = s0, s2 = s0, s3 = s0;
  float s256 = 0.f;
  float2 rs[5][4];                             // saved rows (static-indexed only)
  float rn[5];
  #pragma unroll
  for (int q = 0; q < 5; ++q) {
    rs[q][0] = rs[q][1] = rs[q][2] = rs[q][3] = mkf2(0.f, 0.f);
    rn[q] = 0.f;
  }

  if (c == 0) {                                // exact init: s_0 = IMP_0 (row k=1)
    const float4* r4 = (const float4*)IMP;
    float4 a = r4[2 * l], bb = r4[2 * l + 1];
    s0 = mkf2(a.x, a.y);  s1 = mkf2(a.z, a.w);
    s2 = mkf2(bb.x, bb.y); s3 = mkf2(bb.z, bb.w);
    s256 = IMP[512];
    if (w == 1) { rs[0][0]=s0; rs[0][1]=s1; rs[0][2]=s2; rs[0][3]=s3; rn[0]=s256; }
  }

  StepBuf b0, b1, b2, b3;
  loadStep(b0, w0 + 0, l, tf_re, tf_im, IMP);
  loadStep(b1, w0 + 1, l, tf_re, tf_im, IMP);
  loadStep(b2, w0 + 2, l, tf_re, tf_im, IMP);
  loadStep(b3, w0 + 3, l, tf_re, tf_im, IMP);

  #define SAVEIF(KK) \
    if ((KK) >= 0 && (KK) <= 16 && (((KK) & 3) == w)) { \
      const int _q = (((KK) > 0 ? (KK) : 0)) >> 2; \
      rs[_q][0]=s0; rs[_q][1]=s1; rs[_q][2]=s2; rs[_q][3]=s3; rn[_q]=s256; }

  #define STEP(BUF, M, KK) { \
    const float tfr_ = __shfl(t256v, (M)); \
    const float im2_ = __shfl(i256v, (M)); \
    doStep(BUF, l, tfr_, im2_, s0, s1, s2, s3, s256); \
    SAVEIF(KK) \
    { int nx = w0 + (M) + 4; nx = (nx > lastStep) ? lastStep : nx; \
      loadStep(BUF, nx, l, tf_re, tf_im, IMP); } }

  if (c > 0) {                                 // 24 steps: 7 warm, k = m-7
    STEP(b0,0,-7)  STEP(b1,1,-6)  STEP(b2,2,-5)  STEP(b3,3,-4)
    STEP(b0,4,-3)  STEP(b1,5,-2)  STEP(b2,6,-1)  STEP(b3,7,0)
    STEP(b0,8,1)   STEP(b1,9,2)   STEP(b2,10,3)  STEP(b3,11,4)
    STEP(b0,12,5)  STEP(b1,13,6)  STEP(b2,14,7)  STEP(b3,15,8)
    STEP(b0,16,9)  STEP(b1,17,10) STEP(b2,18,11) STEP(b3,19,12)
    STEP(b0,20,13) STEP(b1,21,14) STEP(b2,22,15) STEP(b3,23,16)
  } else {                                     // 16 steps (step 15 padding), k = m+2
    STEP(b0,0,2)   STEP(b1,1,3)   STEP(b2,2,4)   STEP(b3,3,5)
    STEP(b0,4,6)   STEP(b1,5,7)   STEP(b2,6,8)   STEP(b3,7,9)
    STEP(b0,8,10)  STEP(b1,9,11)  STEP(b2,10,12) STEP(b3,11,13)
    STEP(b0,12,14) STEP(b1,13,15) STEP(b2,14,16) STEP(b3,15,17)
  }
  #undef STEP
  #undef SAVEIF

  // ---- iFFT phase: wave w transforms its own rows k = 4q + w ---------------
  float cu, su; sincosf(0.02454369260617026f * (float)l, &su, &cu);
  const float clC = cu * cu - su * su, slC = 2.f * cu * su;
  float Tc, Ts; sincosf(-0.09817477042468103f * (float)l, &Ts, &Tc);
  constexpr float crC[4] = {1.f, 0.9999247018391445f, 0.9996988186962042f, 0.9993223845883495f};
  constexpr float srC[4] = {0.f, 0.0122715382857199f, 0.0245412285229123f, 0.0368072229413588f};
  const float ISC = 0.08838834764831845f;      // sqrt(512)/256
  const int pidx = (64 - l) & 63;

  #pragma unroll
  for (int q = 0; q < 5; ++q) {
    const int k = 4 * q + w;
    if (k <= 16) {                             // wave-uniform condition
      float2 W0 = rs[q][0], W1 = rs[q][1], W2 = rs[q][2], W3 = rs[q][3];
      float w256 = rn[q];
      float2 W[4] = {W0, W1, W2, W3};
      float2 Wm[4];
      Wm[0].x = __shfl(W0.x, pidx);
      Wm[0].y = __shfl(W0.y, pidx);
      if (l == 0) Wm[0] = mkf2(w256, 0.f);
      Wm[1].x = __shfl_xor(W3.x, 63);  Wm[1].y = __shfl_xor(W3.y, 63);
      Wm[2].x = __shfl_xor(W2.x, 63);  Wm[2].y = __shfl_xor(W2.y, 63);
      Wm[3].x = __shfl_xor(W1.x, 63);  Wm[3].y = __shfl_xor(W1.y, 63);
      float2 v[4];
      #pragma unroll
      for (int rr = 0; rr < 4; ++rr) {
        float Ex = 0.5f * (W[rr].x + Wm[rr].x), Ey = 0.5f * (W[rr].y - Wm[rr].y);
        float Dx = W[rr].x - Wm[rr].x,          Dy = W[rr].y + Wm[rr].y;
        float cc  = clC * crC[rr] - slC * srC[rr];
        float sn  = clC * srC[rr] + slC * crC[rr];
        float Ox = 0.5f * (cc * Dx - sn * Dy);
        float Oy = 0.5f * (cc * Dy + sn * Dx);
        v[rr] = mkf2(Ex - Oy, Ey + Ox);
      }
      waveFFT256<+1>(v, l, Tc, Ts, cu, su);
      #pragma unroll
      for (int rr = 0; rr < 4; ++rr)
        ybuf[k][64 * rr + l] = mkf2(v[rr].x * ISC, v[rr].y * ISC);
    }
  }

  __syncthreads();

  // ---- OA: segment j0+k = ybuf[k+1] head + ybuf[k] tail --------------------
  float2* out2 = (float2*)out;
  const size_t base = (size_t)j0 * 128;
  for (int idx = tid; idx < 2048; idx += 256) {
    const int k = idx >> 7, t2 = idx & 127;
    float2 a = ybuf[k + 1][t2];
    float2 p = ybuf[k][128 + t2];
    out2[base + idx] = mkf2(a.x + p.x, a.y + p.y);
  }
}

// ---------------- launch ----------------
extern "C" void kernel_launch(void* const* d_in, const int* in_sizes, int n_in,
                              void* d_out, int out_size, void* d_ws, size_t ws_size,
                              hipStream_t stream) {
  const float* env    = (const float*)d_in[1];
  const float* tf_re  = (const float*)d_in[2];
  const float* tf_im  = (const float*)d_in[3];
  const float* etf_re = (const float*)d_in[4];
  const float* etf_im = (const float*)d_in[5];
  const float* noise  = (const float*)d_in[6];
  float* out = (float*)d_out;

  float* wsf = (float*)d_ws;
  float* IMP  = wsf;                                   // (N_STEPS+1) x ROWF
  float* T256 = wsf + (size_t)(N_STEPS + 1) * ROWF;    // N_STEPS floats
  float* I256 = T256 + N_STEPS;                        // N_STEPS+1 floats
  // ws use: 10241 * 2112 B + ~82 KB ~= 21.7 MB

  kernA<<<(N_STEPS / 4) + 1, 256, 0, stream>>>(env, noise, tf_re, etf_re, etf_im,
                                               IMP, T256, I256);
  kernBC<<<N_STEPS / LCH, 256, 0, stream>>>(tf_re, tf_im, IMP, T256, I256, out);
}